// Round 7
// baseline (4663.582 us; speedup 1.0000x reference)
//
#include <hip/hip_runtime.h>
#include <stdint.h>

// FPS: B=8, N=131072, 3 coords, m=1024.
// 32 blocks/batch (bid%8 -> same XCD under round-robin dispatch); 16 pts/thread
// in registers; xyz mirrored in LDS for the publisher.
// Cross-block reduce via XCD-L2 atomics (no sc1 => executes at local L2):
//   key[par] : global_atomic_umax_x2 of akey = s<<49 | distBits<<17 | rel.
//              Parity-buffered (s&1); within a line s jumps by 2 => monotone,
//              never reset. A slow reader of s cannot see s+2: any s+2 publish
//              requires count>=32(s+1) which requires OUR barrier after s.
//   count    : single monotone line; publisher: payload store + atomic max,
//              s_waitcnt vmcnt(0), atomic add(1). So count>=32s  =>  all 32
//              maxes AND payload stores for s landed (induction: first time
//              count reaches 32s, every block has posted exactly s adds).
// RACE-FREE DETECTION (fix for R5): wave0 polls COUNT ONLY; after observing
// count>=32s (vmcnt(0) completed), it issues the key+payload load -- serviced
// by L2 strictly after all maxes landed => final. No concurrent-snapshot use.
// Misplacement safety: bounded poll -> sticky agent-scope fallback; wave1
// maintains agent-scope backup slots EVERY iteration regardless of mode.
// 0xAA ws poison: payload tag 0xAAAAAAAA != s in {1,2}; ic tag 682 != {1,2};
// key/count lines are memset(0) at launch (monotone within a launch).

#define BATCHES 8
#define NPTS    131072
#define MSEL    1024
#define NBLK    32                 // blocks per batch
#define CHUNK   (NPTS / NBLK)      // 4096 points per block
#define NTH     256
#define PPT     (CHUNK / NTH)      // 16 points per thread (registers)
#define NWAVE   (NTH / 64)
#define L2_TIMEOUT_ROUNDS 4000     // ~0.5ms once, then sticky agent path

typedef unsigned int       u32;
typedef unsigned long long u64;
typedef u32 u32x4 __attribute__((ext_vector_type(4)));

__global__ __launch_bounds__(NTH, 1) void fps_kernel(
    const float* __restrict__ pts,   // [B][N][3]
    float* __restrict__ out,         // [B*M] idx-as-float, then [B*M*3] xyz
    char* __restrict__ ws,           // ctl(4KB) | payloads | icslots
    int pad)                         // payload slot stride (128 or 32)
{
    __shared__ float lx[CHUNK], ly[CHUNK], lz[CHUNK];
    __shared__ u64 wkey[NWAVE];
    __shared__ float curs[4];

    const int bid   = blockIdx.x;
    const int b     = bid & (BATCHES - 1);
    const int blk   = bid / BATCHES;
    const int tid   = threadIdx.x;
    const int gbase = blk * CHUNK;
    const float* bp = pts + (size_t)b * NPTS * 3;

    // per-batch control region, 512B: key[0] @0, key[1] @128, count @256
    char* ctl  = ws + (size_t)b * 512;
    u32*  cntp = (u32*)(ctl + 256);
    char* plb0 = ws + 4096;
    u64*  ic   = (u64*)(ws + 4096 + (size_t)2 * BATCHES * NBLK * pad);

    // Stage 16 points/thread into registers + LDS xyz mirror (publisher use).
    float px[PPT], py[PPT], pz[PPT], md[PPT];
    #pragma unroll
    for (int k = 0; k < PPT; ++k) {
        const int j = k * NTH + tid;
        const size_t gi = (size_t)(gbase + j) * 3;
        px[k] = bp[gi + 0];
        py[k] = bp[gi + 1];
        pz[k] = bp[gi + 2];
        md[k] = 1e10f;
        lx[j] = px[k]; ly[j] = py[k]; lz[j] = pz[k];
    }
    const u32 relt = (u32)(NPTS - 1) - (u32)(gbase + tid);

    float cx = bp[0], cy = bp[1], cz = bp[2];
    if (blk == 0 && tid == 0) {
        out[b * MSEL] = 0.0f;
        float* oxyz = out + BATCHES * MSEL;
        oxyz[(size_t)(b * MSEL) * 3 + 0] = cx;
        oxyz[(size_t)(b * MSEL) * 3 + 1] = cy;
        oxyz[(size_t)(b * MSEL) * 3 + 2] = cz;
    }
    __syncthreads();

    const int wv = tid >> 6;
    const int ln = tid & 63;
    bool useAgent = false;

    for (int s = 1; s < MSEL; ++s) {
        // ---- min-dist update + local argmax; key = distBits<<17 | rel ----
        u64 bk = 0ull;
        #pragma unroll
        for (int k = 0; k < PPT; ++k) {
            float dx = __fsub_rn(px[k], cx);
            float dy = __fsub_rn(py[k], cy);
            float dz = __fsub_rn(pz[k], cz);
            float d  = __fadd_rn(__fadd_rn(__fmul_rn(dx, dx), __fmul_rn(dy, dy)),
                                 __fmul_rn(dz, dz));
            float nm = fminf(md[k], d);
            md[k] = nm;
            u64 key = ((u64)__float_as_uint(nm) << 17)
                    | (u64)(relt - (u32)(k * NTH));
            bk = (bk > key) ? bk : key;
        }
        #pragma unroll
        for (int o = 32; o > 0; o >>= 1) {
            u64 t = __shfl_xor(bk, o, 64);
            bk = (bk > t) ? bk : t;
        }
        if (ln == 0) wkey[wv] = bk;
        __syncthreads();

        const u32 tag = (u32)s;                 // 1..1023
        const int par = s & 1;
        u64*  keyp   = (u64*)(ctl + par * 128);
        char* plbase = plb0 + ((size_t)(par * BATCHES + b) * NBLK) * pad;
        const size_t icb = (size_t)(par * BATCHES + b) * NBLK;

        // ---- wave1 lane0: publish (payload, max, waitcnt, add, backup) ----
        if (wv == 1 && ln == 0) {
            u64 k0 = wkey[0];
            #pragma unroll
            for (int w = 1; w < NWAVE; ++w) k0 = (k0 > wkey[w]) ? k0 : wkey[w];
            const u32 rel = (u32)(k0 & 0x1FFFFull);
            const int j = (int)((u32)(NPTS - 1) - rel) - gbase;
            u32x4 pl;
            pl.x = __float_as_uint(lx[j]);
            pl.y = __float_as_uint(ly[j]);
            pl.z = __float_as_uint(lz[j]);
            pl.w = tag;
            const u64 akey = ((u64)tag << 49) | k0;
            asm volatile(
                "global_store_dwordx4 %0, %1, off sc0\n\t"
                "global_atomic_umax_x2 %2, %3, off\n\t"
                "s_waitcnt vmcnt(0)\n\t"
                "global_atomic_add %4, %5, off"
                :: "v"(plbase + (size_t)blk * pad), "v"(pl),
                   "v"(keyp), "v"(akey),
                   "v"(cntp), "v"(1u)
                : "memory");
            // agent-scope backup (fallback path), maintained EVERY iteration
            const u64 sv = ((k0 >> 17) << 27) | ((u64)rel << 10) | (u64)tag;
            __hip_atomic_store(&ic[icb + blk], sv,
                               __ATOMIC_RELAXED, __HIP_MEMORY_SCOPE_AGENT);
        }

        // ---- wave0: two-phase detect (count poll, THEN final load) ----
        if (wv == 0) {
            bool det = false;
            u32 widx = 0; float x = 0.f, y = 0.f, z = 0.f;
            if (!useAgent) {
                const u32 target = 32u * tag;
                int r = 0; u32 c;
                for (;;) {
                    asm volatile("global_load_dword %0, %1, off sc0\n\t"
                                 "s_waitcnt vmcnt(0)"
                                 : "=v"(c) : "v"(cntp) : "memory");
                    if (c >= target) { det = true; break; }   // wave-uniform
                    if (++r >= L2_TIMEOUT_ROUNDS) { useAgent = true; break; }
                    if (r > 16) __builtin_amdgcn_s_sleep(1);
                }
            }
            if (det) {
                // issued AFTER the detecting load completed => sees all maxes
                u64 kf = 0ull; u32x4 PL = {0, 0, 0, 0};
                if (ln < 32) {
                    const char* plp = plbase + (size_t)ln * pad;
                    asm volatile(
                        "global_load_dwordx2 %0, %2, off sc0\n\t"
                        "global_load_dwordx4 %1, %3, off sc0\n\t"
                        "s_waitcnt vmcnt(0)"
                        : "=&v"(kf), "=&v"(PL)
                        : "v"(keyp), "v"(plp)
                        : "memory");
                }
                const u32 klo  = (u32)__shfl((int)(u32)kf, 0, 64);
                const u32 khi  = (u32)__shfl((int)(u32)(kf >> 32), 0, 64);
                const u32 ktag = khi >> 17;
                const u32 rel  = klo & 0x1FFFFu;
                widx = (u32)(NPTS - 1) - rel;
                const int wblk = (int)(widx >> 12);       // /CHUNK
                x = __shfl(__uint_as_float(PL.x), wblk, 64);
                y = __shfl(__uint_as_float(PL.y), wblk, 64);
                z = __shfl(__uint_as_float(PL.z), wblk, 64);
                const u32 wtag = (u32)__shfl((int)PL.w, wblk, 64);
                if (ktag != tag || wtag != tag) {   // should never fire
                    det = false; useAgent = true;
                }
            }
            if (det) {
                if (ln == 0) {
                    curs[0] = x; curs[1] = y; curs[2] = z;
                    if (blk == 0) {
                        out[b * MSEL + s] = (float)widx;
                        float* oxyz = out + BATCHES * MSEL;
                        oxyz[(size_t)(b * MSEL + s) * 3 + 0] = x;
                        oxyz[(size_t)(b * MSEL + s) * 3 + 1] = y;
                        oxyz[(size_t)(b * MSEL + s) * 3 + 2] = z;
                    }
                }
            } else {
                // ---- sticky agent-scope fallback (R3-proven) ----
                u64 ak = 0ull;
                for (;;) {
                    if (ln < NBLK)
                        ak = __hip_atomic_load(&ic[icb + ln], __ATOMIC_RELAXED,
                                               __HIP_MEMORY_SCOPE_AGENT);
                    if (__all((ln >= NBLK) | ((u32)(ak & 1023ull) ==
                                              (tag & 1023u))))
                        break;
                    __builtin_amdgcn_s_sleep(1);
                }
                #pragma unroll
                for (int o = 16; o > 0; o >>= 1) {
                    u64 t = __shfl_xor(ak, o, 64);
                    ak = (ak > t) ? ak : t;
                }
                const u32 fwidx =
                    (u32)(NPTS - 1) - (u32)((ak >> 10) & 0x1FFFFull);
                if (ln < 3) {
                    const float v = bp[(size_t)fwidx * 3 + ln];
                    curs[ln] = v;
                    if (blk == 0)
                        out[BATCHES * MSEL + (size_t)(b * MSEL + s) * 3 + ln] = v;
                }
                if (ln == 0 && blk == 0) out[b * MSEL + s] = (float)fwidx;
            }
        }
        __syncthreads();
        cx = curs[0]; cy = curs[1]; cz = curs[2];
    }
}

extern "C" void kernel_launch(void* const* d_in, const int* in_sizes, int n_in,
                              void* d_out, int out_size, void* d_ws, size_t ws_size,
                              hipStream_t stream) {
    const float* pts = (const float*)d_in[0];
    float* out = (float*)d_out;

    // ctl 4KB + payloads 2*8*32*pad + icslots 4KB
    const int pad = (ws_size >= (size_t)(4096 + 2 * BATCHES * NBLK * 128 + 4096))
                        ? 128 : 32;
    // zero the key/count control lines (monotone within a launch)
    hipMemsetAsync(d_ws, 0, 4096, stream);

    fps_kernel<<<dim3(BATCHES * NBLK), dim3(NTH), 0, stream>>>(
        pts, out, (char*)d_ws, pad);
}

// Round 9
// 3861.059 us; speedup vs baseline: 1.2079x; 1.2079x over previous
//
#include <hip/hip_runtime.h>
#include <stdint.h>

// FPS: B=8, N=131072, 3, m=1024 -- with EXACT top-2 speculation.
// Round rc publishes each block's top-2 keys (+xyz). Global (K1,K2) via
// 64-lane pair-butterfly. Selection s := K1's point. If
// dist(c2,w1)^2 >= md[c2] (exact f32), K2's point is PROVABLY the next
// selection too (md' <= md pointwise, K'[c2]=K[c2] dominates) -> two
// selections per sync round. All blocks decide uniformly (same bits).
// Slot protocol = R4-proven: per-block tagged 16B+8B groups (tear-free
// dwordx4/x2, sc0 = XCD-L2 coherent), parity double-buffer by rc,
// stop-on-fresh polling, no fences. Agent-scope key backups (both keys)
// + sticky timeout fallback keep any block->XCD placement correct
// (fallback gathers xyz from pts => bit-identical decisions).
// Poison: slot tags 682 != rc in {1,2}; parity slot for rc seen only
// after being written at rc (first uses rc=1,2). ic same.

#define BATCHES 8
#define NPTS    131072
#define MSEL    1024
#define NBLK    32                 // blocks per batch
#define CHUNK   (NPTS / NBLK)      // 4096
#define NTH     256
#define PPT     (CHUNK / NTH)      // 16
#define NWAVE   (NTH / 64)
#define L2_TIMEOUT_ROUNDS 4000

typedef unsigned int       u32;
typedef unsigned long long u64;
typedef u32 u32x4 __attribute__((ext_vector_type(4)));
typedef u32 u32x2 __attribute__((ext_vector_type(2)));

// top-2 merge of two DISJOINT-set pairs (a1>=a2, b1>=b2)
__device__ __forceinline__ void pmerge(u64& a1, u64& a2, u64 b1, u64 b2) {
    const u64 lo = (a1 < b1) ? a1 : b1;
    const u64 hi = (a1 < b1) ? b1 : a1;
    const u64 m2 = (a2 > b2) ? a2 : b2;
    a1 = hi;
    a2 = (lo > m2) ? lo : m2;
}

__device__ __forceinline__ void st_slot(void* p, u32x4 a, u32x2 b) {
    asm volatile("global_store_dwordx4 %0, %1, off sc0\n\t"
                 "global_store_dwordx2 %2, %3, off sc0"
                 :: "v"((u32*)p), "v"(a), "v"(((u32*)p) + 4), "v"(b)
                 : "memory");
}
__device__ __forceinline__ void ld_slot(const void* p, u32x4& a, u32x2& b) {
    u32x4 ra; u32x2 rb;
    asm volatile("global_load_dwordx4 %0, %2, off sc0\n\t"
                 "global_load_dwordx2 %1, %3, off sc0\n\t"
                 "s_waitcnt vmcnt(0)"
                 : "=&v"(ra), "=&v"(rb)
                 : "v"((const u32*)p), "v"(((const u32*)p) + 4)
                 : "memory");
    a = ra; b = rb;
}

__global__ __launch_bounds__(NTH, 1) void fps_kernel(
    const float* __restrict__ pts,   // [B][N][3]
    float* __restrict__ out,         // [B*M] idx-as-float, then [B*M*3] xyz
    char* __restrict__ ws,
    int pad)
{
    __shared__ float lx[CHUNK], ly[CHUNK], lz[CHUNK];
    __shared__ u64 wkey[NWAVE][2];
    __shared__ float curs[8];        // x1,y1,z1, x2,y2,z2, specFlag

    const int bid   = blockIdx.x;
    const int b     = bid & (BATCHES - 1);
    const int blk   = bid / BATCHES;
    const int tid   = threadIdx.x;
    const int gbase = blk * CHUNK;
    const float* bp = pts + (size_t)b * NPTS * 3;

    // slots: [2 parity][BATCHES][64] x pad ; then ic: [2][BATCHES][64] u64
    char* plb0 = ws;
    u64*  ic   = (u64*)(ws + (size_t)2 * BATCHES * 64 * pad);

    float px[PPT], py[PPT], pz[PPT], md[PPT];
    #pragma unroll
    for (int k = 0; k < PPT; ++k) {
        const int j = k * NTH + tid;
        const size_t gi = (size_t)(gbase + j) * 3;
        px[k] = bp[gi + 0];
        py[k] = bp[gi + 1];
        pz[k] = bp[gi + 2];
        md[k] = 1e10f;
        lx[j] = px[k]; ly[j] = py[k]; lz[j] = pz[k];
    }
    const u32 relt = (u32)(NPTS - 1) - (u32)(gbase + tid);

    float c1x = bp[0], c1y = bp[1], c1z = bp[2];
    float c2x = c1x, c2y = c1y, c2z = c1z;
    bool have2 = false;
    if (blk == 0 && tid == 0) {
        out[b * MSEL] = 0.0f;
        float* oxyz = out + BATCHES * MSEL;
        oxyz[(size_t)(b * MSEL) * 3 + 0] = c1x;
        oxyz[(size_t)(b * MSEL) * 3 + 1] = c1y;
        oxyz[(size_t)(b * MSEL) * 3 + 2] = c1z;
    }
    __syncthreads();

    const int wv = tid >> 6;
    const int ln = tid & 63;
    bool useAgent = false;
    int s = 1;

    for (int rc = 1; s < MSEL; ++rc) {
        // ---- md update (1 or 2 new points, exact order) + top-2 track ----
        u64 a1 = 0ull, a2 = 0ull;
        if (have2) {
            #pragma unroll
            for (int k = 0; k < PPT; ++k) {
                float dx = __fsub_rn(px[k], c1x);
                float dy = __fsub_rn(py[k], c1y);
                float dz = __fsub_rn(pz[k], c1z);
                float d1 = __fadd_rn(__fadd_rn(__fmul_rn(dx, dx),
                                               __fmul_rn(dy, dy)),
                                     __fmul_rn(dz, dz));
                float ex = __fsub_rn(px[k], c2x);
                float ey = __fsub_rn(py[k], c2y);
                float ez = __fsub_rn(pz[k], c2z);
                float d2 = __fadd_rn(__fadd_rn(__fmul_rn(ex, ex),
                                               __fmul_rn(ey, ey)),
                                     __fmul_rn(ez, ez));
                float nm = fminf(fminf(md[k], d1), d2);   // == ref sequential
                md[k] = nm;
                u64 key = ((u64)__float_as_uint(nm) << 17)
                        | (u64)(relt - (u32)(k * NTH));
                const bool gt = key > a1;
                const u64 mx2 = (key > a2) ? key : a2;
                a2 = gt ? a1 : mx2;
                a1 = gt ? key : a1;
            }
        } else {
            #pragma unroll
            for (int k = 0; k < PPT; ++k) {
                float dx = __fsub_rn(px[k], c1x);
                float dy = __fsub_rn(py[k], c1y);
                float dz = __fsub_rn(pz[k], c1z);
                float d1 = __fadd_rn(__fadd_rn(__fmul_rn(dx, dx),
                                               __fmul_rn(dy, dy)),
                                     __fmul_rn(dz, dz));
                float nm = fminf(md[k], d1);
                md[k] = nm;
                u64 key = ((u64)__float_as_uint(nm) << 17)
                        | (u64)(relt - (u32)(k * NTH));
                const bool gt = key > a1;
                const u64 mx2 = (key > a2) ? key : a2;
                a2 = gt ? a1 : mx2;
                a1 = gt ? key : a1;
            }
        }
        // wave pair-butterfly (disjoint sets at every level)
        #pragma unroll
        for (int o = 32; o > 0; o >>= 1) {
            u64 b1 = __shfl_xor(a1, o, 64);
            u64 b2 = __shfl_xor(a2, o, 64);
            pmerge(a1, a2, b1, b2);
        }
        if (ln == 0) { wkey[wv][0] = a1; wkey[wv][1] = a2; }
        __syncthreads();

        const u32 tag = (u32)rc;            // 1..1023, unique per round
        const int par = rc & 1;
        char* plbase = plb0 + ((size_t)(par * BATCHES + b) * 64) * pad;
        const size_t icb = (size_t)(par * BATCHES + b) * 64;

        // ---- wave1 lane0: publish block top-2 (P,S slots) + ic backup ----
        if (wv == 1 && ln == 0) {
            u64 k1 = wkey[0][0], k2 = wkey[0][1];
            #pragma unroll
            for (int w = 1; w < NWAVE; ++w) pmerge(k1, k2, wkey[w][0], wkey[w][1]);
            const u32 rel1 = (u32)(k1 & 0x1FFFFull);
            const u32 rel2 = (u32)(k2 & 0x1FFFFull);
            const int j1 = (int)((u32)(NPTS - 1) - rel1) - gbase;
            const int j2 = (int)((u32)(NPTS - 1) - rel2) - gbase;
            u32x4 A; u32x2 Bv;
            A.x = (u32)(k1 >> 17); A.y = (rel1 << 10) | tag;
            A.z = __float_as_uint(lx[j1]); A.w = __float_as_uint(ly[j1]);
            Bv.x = __float_as_uint(lz[j1]); Bv.y = tag;
            st_slot(plbase + (size_t)blk * pad, A, Bv);
            A.x = (u32)(k2 >> 17); A.y = (rel2 << 10) | tag;
            A.z = __float_as_uint(lx[j2]); A.w = __float_as_uint(ly[j2]);
            Bv.x = __float_as_uint(lz[j2]); Bv.y = tag;
            st_slot(plbase + (size_t)(32 + blk) * pad, A, Bv);
            __hip_atomic_store(&ic[icb + 2 * blk],
                               ((k1 >> 17) << 27) | ((u64)rel1 << 10) | tag,
                               __ATOMIC_RELAXED, __HIP_MEMORY_SCOPE_AGENT);
            __hip_atomic_store(&ic[icb + 2 * blk + 1],
                               ((k2 >> 17) << 27) | ((u64)rel2 << 10) | tag,
                               __ATOMIC_RELAXED, __HIP_MEMORY_SCOPE_AGENT);
        }

        // ---- wave0: poll 64 slots (lane ln <-> slot ln), reduce, decide ----
        if (wv == 0) {
            u32x4 LA = {0, 0, 0, 0}; u32x2 LB = {0, 0};
            bool done = false;
            if (!useAgent) {
                const char* myp = plbase + (size_t)ln * pad;
                int r = 0;
                for (;;) {
                    if (!done) {
                        u32x4 ta; u32x2 tb;
                        ld_slot(myp, ta, tb);
                        if (((ta.y & 1023u) == tag) & (tb.y == tag)) {
                            LA = ta; LB = tb; done = true;
                        }
                    }
                    if (__all(done)) break;
                    if (++r >= L2_TIMEOUT_ROUNDS) { useAgent = true; break; }
                    if (r > 16) __builtin_amdgcn_s_sleep(1);
                }
            }
            if (!useAgent) {
                u64 k1 = ((u64)LA.x << 17) | (u64)(LA.y >> 10);
                u64 k2 = 0ull;
                #pragma unroll
                for (int o = 32; o > 0; o >>= 1) {
                    u64 b1 = __shfl_xor(k1, o, 64);
                    u64 b2 = __shfl_xor(k2, o, 64);
                    pmerge(k1, k2, b1, b2);
                }
                const u32 rel1  = (u32)(k1 & 0x1FFFFull);
                const u32 rel2  = (u32)(k2 & 0x1FFFFull);
                const u32 widx1 = (u32)(NPTS - 1) - rel1;
                const u32 widx2 = (u32)(NPTS - 1) - rel2;
                const int wb1   = (int)(widx1 >> 12);
                const int wbb   = (int)(widx2 >> 12);
                const int src2  = (wbb == wb1) ? (32 + wb1) : wbb;
                const float x1 = __shfl(__uint_as_float(LA.z), wb1, 64);
                const float y1 = __shfl(__uint_as_float(LA.w), wb1, 64);
                const float z1 = __shfl(__uint_as_float(LB.x), wb1, 64);
                const float x2 = __shfl(__uint_as_float(LA.z), src2, 64);
                const float y2 = __shfl(__uint_as_float(LA.w), src2, 64);
                const float z2 = __shfl(__uint_as_float(LB.x), src2, 64);
                // exact speculation test: dist(c2,w1)^2 >= md[c2]
                const float ddx = __fsub_rn(x2, x1);
                const float ddy = __fsub_rn(y2, y1);
                const float ddz = __fsub_rn(z2, z1);
                const float dd  = __fadd_rn(__fadd_rn(__fmul_rn(ddx, ddx),
                                                      __fmul_rn(ddy, ddy)),
                                            __fmul_rn(ddz, ddz));
                const bool spec = (__float_as_uint(dd) >= (u32)(k2 >> 17))
                                  && (s + 1 < MSEL);
                if (ln == 0) {
                    curs[0] = x1; curs[1] = y1; curs[2] = z1;
                    curs[3] = x2; curs[4] = y2; curs[5] = z2;
                    curs[6] = spec ? 1.0f : 0.0f;
                    if (blk == 0) {
                        out[b * MSEL + s] = (float)widx1;
                        float* oxyz = out + BATCHES * MSEL;
                        oxyz[(size_t)(b * MSEL + s) * 3 + 0] = x1;
                        oxyz[(size_t)(b * MSEL + s) * 3 + 1] = y1;
                        oxyz[(size_t)(b * MSEL + s) * 3 + 2] = z1;
                        if (spec) {
                            out[b * MSEL + s + 1] = (float)widx2;
                            oxyz[(size_t)(b * MSEL + s + 1) * 3 + 0] = x2;
                            oxyz[(size_t)(b * MSEL + s + 1) * 3 + 1] = y2;
                            oxyz[(size_t)(b * MSEL + s + 1) * 3 + 2] = z2;
                        }
                    }
                }
            } else {
                // ---- sticky agent-scope fallback: both keys, xyz from pts --
                const int ii = (ln < 32) ? (2 * ln) : (2 * (ln - 32) + 1);
                u64 sv = 0ull;
                for (;;) {
                    sv = __hip_atomic_load(&ic[icb + ii], __ATOMIC_RELAXED,
                                           __HIP_MEMORY_SCOPE_AGENT);
                    if (__all((u32)(sv & 1023ull) == (tag & 1023u))) break;
                    __builtin_amdgcn_s_sleep(1);
                }
                u64 k1 = ((sv >> 27) << 17) | ((sv >> 10) & 0x1FFFFull);
                u64 k2 = 0ull;
                #pragma unroll
                for (int o = 32; o > 0; o >>= 1) {
                    u64 b1 = __shfl_xor(k1, o, 64);
                    u64 b2 = __shfl_xor(k2, o, 64);
                    pmerge(k1, k2, b1, b2);
                }
                const u32 widx1 = (u32)(NPTS - 1) - (u32)(k1 & 0x1FFFFull);
                const u32 widx2 = (u32)(NPTS - 1) - (u32)(k2 & 0x1FFFFull);
                if (ln == 0) {
                    const float x1 = bp[(size_t)widx1 * 3 + 0];
                    const float y1 = bp[(size_t)widx1 * 3 + 1];
                    const float z1 = bp[(size_t)widx1 * 3 + 2];
                    const float x2 = bp[(size_t)widx2 * 3 + 0];
                    const float y2 = bp[(size_t)widx2 * 3 + 1];
                    const float z2 = bp[(size_t)widx2 * 3 + 2];
                    const float ddx = __fsub_rn(x2, x1);
                    const float ddy = __fsub_rn(y2, y1);
                    const float ddz = __fsub_rn(z2, z1);
                    const float dd  = __fadd_rn(__fadd_rn(__fmul_rn(ddx, ddx),
                                                          __fmul_rn(ddy, ddy)),
                                                __fmul_rn(ddz, ddz));
                    const bool spec = (__float_as_uint(dd) >= (u32)(k2 >> 17))
                                      && (s + 1 < MSEL);
                    curs[0] = x1; curs[1] = y1; curs[2] = z1;
                    curs[3] = x2; curs[4] = y2; curs[5] = z2;
                    curs[6] = spec ? 1.0f : 0.0f;
                    if (blk == 0) {
                        out[b * MSEL + s] = (float)widx1;
                        float* oxyz = out + BATCHES * MSEL;
                        oxyz[(size_t)(b * MSEL + s) * 3 + 0] = x1;
                        oxyz[(size_t)(b * MSEL + s) * 3 + 1] = y1;
                        oxyz[(size_t)(b * MSEL + s) * 3 + 2] = z1;
                        if (spec) {
                            out[b * MSEL + s + 1] = (float)widx2;
                            oxyz[(size_t)(b * MSEL + s + 1) * 3 + 0] = x2;
                            oxyz[(size_t)(b * MSEL + s + 1) * 3 + 1] = y2;
                            oxyz[(size_t)(b * MSEL + s + 1) * 3 + 2] = z2;
                        }
                    }
                }
            }
        }
        __syncthreads();
        c1x = curs[0]; c1y = curs[1]; c1z = curs[2];
        c2x = curs[3]; c2y = curs[4]; c2z = curs[5];
        have2 = (curs[6] != 0.0f);
        s += 1 + (have2 ? 1 : 0);
    }
}

extern "C" void kernel_launch(void* const* d_in, const int* in_sizes, int n_in,
                              void* d_out, int out_size, void* d_ws, size_t ws_size,
                              hipStream_t stream) {
    const float* pts = (const float*)d_in[0];
    float* out = (float*)d_out;

    // slots 2*8*64*pad + ic 8KB
    int pad = 32;
    if (ws_size >= (size_t)(2 * BATCHES * 64 * 128 + 8192 + 1024)) pad = 128;
    else if (ws_size >= (size_t)(2 * BATCHES * 64 * 64 + 8192 + 1024)) pad = 64;

    fps_kernel<<<dim3(BATCHES * NBLK), dim3(NTH), 0, stream>>>(
        pts, out, (char*)d_ws, pad);
}

// Round 10
// 3407.633 us; speedup vs baseline: 1.3686x; 1.1331x over previous
//
#include <hip/hip_runtime.h>
#include <stdint.h>

// FPS: B=8, N=131072, 3, m=1024 -- EXACT top-2 speculation, 32-slot poll.
// Each round: block publishes its top-2 keys AND both xyz in ONE 48B slot
// (3 self-tagged dwordx4 groups, tear-free, sc0 = XCD-L2 coherent).
// Wave0 lanes 0..31 poll one slot each (stop-on-fresh); 6-level pair-
// butterfly gives global (K1,K2); xyz extracted by shuffles. If
// dist(c2,w1)^2 >= md[c2] (exact f32), K2's point is provably the next
// selection -> 2 selections/round (measured hit ~90% => rounds ~540).
// Wave1 lane0: slot burst. Wave2 lane0: agent-scope ic backups (slow IC
// store-ack drains in a wave nobody polls). Sticky timeout fallback to
// agent path keeps any block->XCD placement correct (xyz from pts =>
// bit-identical decisions). Poison: group tags checked &1023 -> 682, can
// only alias at first uses rc in {1,2}; G2 tag full-width. Safe.

#define BATCHES 8
#define NPTS    131072
#define MSEL    1024
#define NBLK    32                 // blocks per batch
#define CHUNK   (NPTS / NBLK)      // 4096
#define NTH     256
#define PPT     (CHUNK / NTH)      // 16
#define NWAVE   (NTH / 64)
#define L2_TIMEOUT_ROUNDS 4000

typedef unsigned int       u32;
typedef unsigned long long u64;
typedef u32 u32x4 __attribute__((ext_vector_type(4)));

// top-2 merge of two DISJOINT-set pairs (a1>=a2, b1>=b2)
__device__ __forceinline__ void pmerge(u64& a1, u64& a2, u64 b1, u64 b2) {
    const u64 lo = (a1 < b1) ? a1 : b1;
    const u64 hi = (a1 < b1) ? b1 : a1;
    const u64 m2 = (a2 > b2) ? a2 : b2;
    a1 = hi;
    a2 = (lo > m2) ? lo : m2;
}

__global__ __launch_bounds__(NTH, 1) void fps_kernel(
    const float* __restrict__ pts,   // [B][N][3]
    float* __restrict__ out,         // [B*M] idx-as-float, then [B*M*3] xyz
    char* __restrict__ ws,
    int pad)                         // slot stride (>=48)
{
    __shared__ float lx[CHUNK], ly[CHUNK], lz[CHUNK];
    __shared__ u64 wkey[NWAVE][2];
    __shared__ float curs[8];        // x1,y1,z1, x2,y2,z2, specFlag

    const int bid   = blockIdx.x;
    const int b     = bid & (BATCHES - 1);
    const int blk   = bid / BATCHES;
    const int tid   = threadIdx.x;
    const int gbase = blk * CHUNK;
    const float* bp = pts + (size_t)b * NPTS * 3;

    char* plb0 = ws;                                        // [2][B][32]*pad
    u64*  ic   = (u64*)(ws + (size_t)2 * BATCHES * NBLK * pad); // [2][B][64]

    float px[PPT], py[PPT], pz[PPT], md[PPT];
    #pragma unroll
    for (int k = 0; k < PPT; ++k) {
        const int j = k * NTH + tid;
        const size_t gi = (size_t)(gbase + j) * 3;
        px[k] = bp[gi + 0];
        py[k] = bp[gi + 1];
        pz[k] = bp[gi + 2];
        md[k] = 1e10f;
        lx[j] = px[k]; ly[j] = py[k]; lz[j] = pz[k];
    }
    const u32 relt = (u32)(NPTS - 1) - (u32)(gbase + tid);

    float c1x = bp[0], c1y = bp[1], c1z = bp[2];
    float c2x = c1x, c2y = c1y, c2z = c1z;
    bool have2 = false;
    if (blk == 0 && tid == 0) {
        out[b * MSEL] = 0.0f;
        float* oxyz = out + BATCHES * MSEL;
        oxyz[(size_t)(b * MSEL) * 3 + 0] = c1x;
        oxyz[(size_t)(b * MSEL) * 3 + 1] = c1y;
        oxyz[(size_t)(b * MSEL) * 3 + 2] = c1z;
    }
    __syncthreads();

    const int wv = tid >> 6;
    const int ln = tid & 63;
    bool useAgent = false;
    int s = 1;

    for (int rc = 1; s < MSEL; ++rc) {
        // ---- md update (1 or 2 centers, exact ref order) + top-2 track ----
        u64 a1 = 0ull, a2 = 0ull;
        if (have2) {
            #pragma unroll
            for (int k = 0; k < PPT; ++k) {
                float dx = __fsub_rn(px[k], c1x);
                float dy = __fsub_rn(py[k], c1y);
                float dz = __fsub_rn(pz[k], c1z);
                float d1 = __fadd_rn(__fadd_rn(__fmul_rn(dx, dx),
                                               __fmul_rn(dy, dy)),
                                     __fmul_rn(dz, dz));
                float ex = __fsub_rn(px[k], c2x);
                float ey = __fsub_rn(py[k], c2y);
                float ez = __fsub_rn(pz[k], c2z);
                float d2 = __fadd_rn(__fadd_rn(__fmul_rn(ex, ex),
                                               __fmul_rn(ey, ey)),
                                     __fmul_rn(ez, ez));
                float nm = fminf(fminf(md[k], d1), d2);   // == ref sequential
                md[k] = nm;
                u64 key = ((u64)__float_as_uint(nm) << 17)
                        | (u64)(relt - (u32)(k * NTH));
                const bool gt = key > a1;
                const u64 mx2 = (key > a2) ? key : a2;
                a2 = gt ? a1 : mx2;
                a1 = gt ? key : a1;
            }
        } else {
            #pragma unroll
            for (int k = 0; k < PPT; ++k) {
                float dx = __fsub_rn(px[k], c1x);
                float dy = __fsub_rn(py[k], c1y);
                float dz = __fsub_rn(pz[k], c1z);
                float d1 = __fadd_rn(__fadd_rn(__fmul_rn(dx, dx),
                                               __fmul_rn(dy, dy)),
                                     __fmul_rn(dz, dz));
                float nm = fminf(md[k], d1);
                md[k] = nm;
                u64 key = ((u64)__float_as_uint(nm) << 17)
                        | (u64)(relt - (u32)(k * NTH));
                const bool gt = key > a1;
                const u64 mx2 = (key > a2) ? key : a2;
                a2 = gt ? a1 : mx2;
                a1 = gt ? key : a1;
            }
        }
        #pragma unroll
        for (int o = 32; o > 0; o >>= 1) {
            u64 t1 = __shfl_xor(a1, o, 64);
            u64 t2 = __shfl_xor(a2, o, 64);
            pmerge(a1, a2, t1, t2);
        }
        if (ln == 0) { wkey[wv][0] = a1; wkey[wv][1] = a2; }
        __syncthreads();

        const u32 tag = (u32)rc;            // 1..1023
        const int par = rc & 1;
        char* plbase = plb0 + ((size_t)(par * BATCHES + b) * NBLK) * pad;
        const size_t icb = (size_t)(par * BATCHES + b) * 64;

        // ---- wave1: slot burst; wave2: agent ic backups ----
        if ((wv == 1 || wv == 2) && ln == 0) {
            u64 k1 = wkey[0][0], k2 = wkey[0][1];
            #pragma unroll
            for (int w = 1; w < NWAVE; ++w)
                pmerge(k1, k2, wkey[w][0], wkey[w][1]);
            const u32 rel1 = (u32)(k1 & 0x1FFFFull);
            const u32 rel2 = (u32)(k2 & 0x1FFFFull);
            if (wv == 1) {
                const int j1 = (int)((u32)(NPTS - 1) - rel1) - gbase;
                const int j2 = (int)((u32)(NPTS - 1) - rel2) - gbase;
                u32x4 G0, G1, G2;
                G0.x = (u32)(k1 >> 17);        G0.y = (rel1 << 10) | tag;
                G0.z = __float_as_uint(lx[j1]); G0.w = __float_as_uint(ly[j1]);
                G1.x = __float_as_uint(lz[j1]); G1.y = (u32)(k2 >> 17);
                G1.z = (rel2 << 10) | tag;      G1.w = __float_as_uint(lx[j2]);
                G2.x = __float_as_uint(ly[j2]); G2.y = __float_as_uint(lz[j2]);
                G2.z = tag;                     G2.w = 0u;
                u32* p = (u32*)(plbase + (size_t)blk * pad);
                asm volatile(
                    "global_store_dwordx4 %0, %1, off sc0\n\t"
                    "global_store_dwordx4 %2, %3, off sc0\n\t"
                    "global_store_dwordx4 %4, %5, off sc0"
                    :: "v"(p), "v"(G0), "v"(p + 4), "v"(G1), "v"(p + 8), "v"(G2)
                    : "memory");
            } else {
                __hip_atomic_store(&ic[icb + 2 * blk],
                                   ((k1 >> 17) << 27) | ((u64)rel1 << 10) | tag,
                                   __ATOMIC_RELAXED, __HIP_MEMORY_SCOPE_AGENT);
                __hip_atomic_store(&ic[icb + 2 * blk + 1],
                                   ((k2 >> 17) << 27) | ((u64)rel2 << 10) | tag,
                                   __ATOMIC_RELAXED, __HIP_MEMORY_SCOPE_AGENT);
            }
        }

        // ---- wave0: poll 32 slots, pair-butterfly, decide ----
        if (wv == 0) {
            u32x4 G0 = {0,0,0,0}, G1 = {0,0,0,0}, G2 = {0,0,0,0};
            bool done = (ln >= NBLK);
            if (!useAgent) {
                const u32* p = (const u32*)(plbase + (size_t)(ln & 31) * pad);
                int r = 0;
                for (;;) {
                    if (!done) {
                        u32x4 t0, t1, t2;
                        asm volatile(
                            "global_load_dwordx4 %0, %3, off sc0\n\t"
                            "global_load_dwordx4 %1, %4, off sc0\n\t"
                            "global_load_dwordx4 %2, %5, off sc0\n\t"
                            "s_waitcnt vmcnt(0)"
                            : "=&v"(t0), "=&v"(t1), "=&v"(t2)
                            : "v"(p), "v"(p + 4), "v"(p + 8)
                            : "memory");
                        if (((t0.y & 1023u) == tag) & ((t1.z & 1023u) == tag)
                            & (t2.z == tag)) {
                            G0 = t0; G1 = t1; G2 = t2; done = true;
                        }
                    }
                    if (__all(done)) break;
                    if (++r >= L2_TIMEOUT_ROUNDS) { useAgent = true; break; }
                    if (r > 16) __builtin_amdgcn_s_sleep(1);
                }
            }
            if (!useAgent) {
                const u64 myk1 = ((u64)G0.x << 17) | (u64)(G0.y >> 10);
                u64 K1 = myk1;
                u64 K2 = ((u64)G1.y << 17) | (u64)(G1.z >> 10);
                #pragma unroll
                for (int o = 32; o > 0; o >>= 1) {
                    u64 t1 = __shfl_xor(K1, o, 64);
                    u64 t2 = __shfl_xor(K2, o, 64);
                    pmerge(K1, K2, t1, t2);
                }
                const u32 widx1 = (u32)(NPTS - 1) - (u32)(K1 & 0x1FFFFull);
                const u32 widx2 = (u32)(NPTS - 1) - (u32)(K2 & 0x1FFFFull);
                const int wb1 = (int)(widx1 >> 12);
                const int wbb = (int)(widx2 >> 12);
                const float x1 = __shfl(__uint_as_float(G0.z), wb1, 64);
                const float y1 = __shfl(__uint_as_float(G0.w), wb1, 64);
                const float z1 = __shfl(__uint_as_float(G1.x), wb1, 64);
                // runner-up: block wbb's primary or secondary?
                const u64  kb = __shfl(myk1, wbb, 64);
                const bool sp = (kb == K2);
                const float xp = __shfl(__uint_as_float(G0.z), wbb, 64);
                const float yp = __shfl(__uint_as_float(G0.w), wbb, 64);
                const float zp = __shfl(__uint_as_float(G1.x), wbb, 64);
                const float xs = __shfl(__uint_as_float(G1.w), wbb, 64);
                const float ys = __shfl(__uint_as_float(G2.x), wbb, 64);
                const float zs = __shfl(__uint_as_float(G2.y), wbb, 64);
                const float x2 = sp ? xp : xs;
                const float y2 = sp ? yp : ys;
                const float z2 = sp ? zp : zs;
                // exact speculation test: dist(c2,w1)^2 >= md[c2]
                const float ddx = __fsub_rn(x2, x1);
                const float ddy = __fsub_rn(y2, y1);
                const float ddz = __fsub_rn(z2, z1);
                const float dd  = __fadd_rn(__fadd_rn(__fmul_rn(ddx, ddx),
                                                      __fmul_rn(ddy, ddy)),
                                            __fmul_rn(ddz, ddz));
                const bool spec = (__float_as_uint(dd) >= (u32)(K2 >> 17))
                                  && (s + 1 < MSEL);
                if (ln == 0) {
                    curs[0] = x1; curs[1] = y1; curs[2] = z1;
                    curs[3] = x2; curs[4] = y2; curs[5] = z2;
                    curs[6] = spec ? 1.0f : 0.0f;
                    if (blk == 0) {
                        out[b * MSEL + s] = (float)widx1;
                        float* oxyz = out + BATCHES * MSEL;
                        oxyz[(size_t)(b * MSEL + s) * 3 + 0] = x1;
                        oxyz[(size_t)(b * MSEL + s) * 3 + 1] = y1;
                        oxyz[(size_t)(b * MSEL + s) * 3 + 2] = z1;
                        if (spec) {
                            out[b * MSEL + s + 1] = (float)widx2;
                            oxyz[(size_t)(b * MSEL + s + 1) * 3 + 0] = x2;
                            oxyz[(size_t)(b * MSEL + s + 1) * 3 + 1] = y2;
                            oxyz[(size_t)(b * MSEL + s + 1) * 3 + 2] = z2;
                        }
                    }
                }
            } else {
                // ---- sticky agent-scope fallback: both keys, xyz from pts --
                const int ii = (ln < 32) ? (2 * ln) : (2 * (ln - 32) + 1);
                u64 sv = 0ull;
                for (;;) {
                    sv = __hip_atomic_load(&ic[icb + ii], __ATOMIC_RELAXED,
                                           __HIP_MEMORY_SCOPE_AGENT);
                    if (__all((u32)(sv & 1023ull) == (tag & 1023u))) break;
                    __builtin_amdgcn_s_sleep(1);
                }
                u64 K1 = ((sv >> 27) << 17) | ((sv >> 10) & 0x1FFFFull);
                u64 K2 = 0ull;
                #pragma unroll
                for (int o = 32; o > 0; o >>= 1) {
                    u64 t1 = __shfl_xor(K1, o, 64);
                    u64 t2 = __shfl_xor(K2, o, 64);
                    pmerge(K1, K2, t1, t2);
                }
                const u32 widx1 = (u32)(NPTS - 1) - (u32)(K1 & 0x1FFFFull);
                const u32 widx2 = (u32)(NPTS - 1) - (u32)(K2 & 0x1FFFFull);
                if (ln == 0) {
                    const float x1 = bp[(size_t)widx1 * 3 + 0];
                    const float y1 = bp[(size_t)widx1 * 3 + 1];
                    const float z1 = bp[(size_t)widx1 * 3 + 2];
                    const float x2 = bp[(size_t)widx2 * 3 + 0];
                    const float y2 = bp[(size_t)widx2 * 3 + 1];
                    const float z2 = bp[(size_t)widx2 * 3 + 2];
                    const float ddx = __fsub_rn(x2, x1);
                    const float ddy = __fsub_rn(y2, y1);
                    const float ddz = __fsub_rn(z2, z1);
                    const float dd  = __fadd_rn(__fadd_rn(__fmul_rn(ddx, ddx),
                                                          __fmul_rn(ddy, ddy)),
                                                __fmul_rn(ddz, ddz));
                    const bool spec = (__float_as_uint(dd) >= (u32)(K2 >> 17))
                                      && (s + 1 < MSEL);
                    curs[0] = x1; curs[1] = y1; curs[2] = z1;
                    curs[3] = x2; curs[4] = y2; curs[5] = z2;
                    curs[6] = spec ? 1.0f : 0.0f;
                    if (blk == 0) {
                        out[b * MSEL + s] = (float)widx1;
                        float* oxyz = out + BATCHES * MSEL;
                        oxyz[(size_t)(b * MSEL + s) * 3 + 0] = x1;
                        oxyz[(size_t)(b * MSEL + s) * 3 + 1] = y1;
                        oxyz[(size_t)(b * MSEL + s) * 3 + 2] = z1;
                        if (spec) {
                            out[b * MSEL + s + 1] = (float)widx2;
                            oxyz[(size_t)(b * MSEL + s + 1) * 3 + 0] = x2;
                            oxyz[(size_t)(b * MSEL + s + 1) * 3 + 1] = y2;
                            oxyz[(size_t)(b * MSEL + s + 1) * 3 + 2] = z2;
                        }
                    }
                }
            }
        }
        __syncthreads();
        c1x = curs[0]; c1y = curs[1]; c1z = curs[2];
        c2x = curs[3]; c2y = curs[4]; c2z = curs[5];
        have2 = (curs[6] != 0.0f);
        s += 1 + (have2 ? 1 : 0);
    }
}

extern "C" void kernel_launch(void* const* d_in, const int* in_sizes, int n_in,
                              void* d_out, int out_size, void* d_ws, size_t ws_size,
                              hipStream_t stream) {
    const float* pts = (const float*)d_in[0];
    float* out = (float*)d_out;

    // slots 2*8*32*pad + ic 8KB
    int pad = 64;
    if (ws_size >= (size_t)(2 * BATCHES * NBLK * 128 + 8192 + 1024)) pad = 128;

    fps_kernel<<<dim3(BATCHES * NBLK), dim3(NTH), 0, stream>>>(
        pts, out, (char*)d_ws, pad);
}

// Round 12
// 2742.118 us; speedup vs baseline: 1.7007x; 1.2427x over previous
//
#include <hip/hip_runtime.h>
#include <stdint.h>

// FPS: B=8, N=131072, 3, m=1024 -- EXACT top-2 speculation + R4 poll protocol.
// Per round: block top-2 (keys + both xyz) in ONE 48B slot = 3 self-tagged
// dwordx4 groups (tear-free, sc0 = XCD-L2 coherent). CRITICAL (R10 lesson):
// wave0 lane0 publishes the slot BEFORE wave0 polls (EXEC-serialized =>
// natural backoff; polls don't hammer L2 during the publish window), and the
// poll sleeps on EVERY miss. Wave1 lane0 maintains agent-scope ic backups.
// Speculation: global (K1,K2) by 6-level pair-butterfly; if dist(c2,w1)^2 >=
// md[c2] (exact f32) then K2's point is provably selection s+1 -> 2/round.
// All blocks decide from identical bits (slot xyz == pts bits) -> uniform.
// Sticky timeout fallback to agent path keeps any block->XCD placement
// correct. Poison: group tags checked vs rc in {1,2} first-uses; 682/0xAA..
// can't alias. md dual-update fminf(fminf(md,d1),d2) == ref sequential.

#define BATCHES 8
#define NPTS    131072
#define MSEL    1024
#define NBLK    32                 // blocks per batch
#define CHUNK   (NPTS / NBLK)      // 4096
#define NTH     256
#define PPT     (CHUNK / NTH)      // 16
#define NWAVE   (NTH / 64)
#define L2_TIMEOUT_ROUNDS 4000

typedef unsigned int       u32;
typedef unsigned long long u64;
typedef u32 u32x4 __attribute__((ext_vector_type(4)));

// top-2 merge of two DISJOINT-set sorted pairs (a1>=a2, b1>=b2)
__device__ __forceinline__ void pmerge(u64& a1, u64& a2, u64 b1, u64 b2) {
    const u64 lo = (a1 < b1) ? a1 : b1;
    const u64 hi = (a1 < b1) ? b1 : a1;
    const u64 m2 = (a2 > b2) ? a2 : b2;
    a1 = hi;
    a2 = (lo > m2) ? lo : m2;
}

__global__ __launch_bounds__(NTH, 1) void fps_kernel(
    const float* __restrict__ pts,   // [B][N][3]
    float* __restrict__ out,         // [B*M] idx-as-float, then [B*M*3] xyz
    char* __restrict__ ws,
    int pad)                         // slot stride (>=48)
{
    __shared__ float lx[CHUNK], ly[CHUNK], lz[CHUNK];
    __shared__ u64 wkey[NWAVE][2];
    __shared__ float curs[8];        // x1,y1,z1, x2,y2,z2, specFlag

    const int bid   = blockIdx.x;
    const int b     = bid & (BATCHES - 1);
    const int blk   = bid / BATCHES;
    const int tid   = threadIdx.x;
    const int gbase = blk * CHUNK;
    const float* bp = pts + (size_t)b * NPTS * 3;

    char* plb0 = ws;                                            // [2][B][32]*pad
    u64*  ic   = (u64*)(ws + (size_t)2 * BATCHES * NBLK * pad); // [2][B][64]

    float px[PPT], py[PPT], pz[PPT], md[PPT];
    #pragma unroll
    for (int k = 0; k < PPT; ++k) {
        const int j = k * NTH + tid;
        const size_t gi = (size_t)(gbase + j) * 3;
        px[k] = bp[gi + 0];
        py[k] = bp[gi + 1];
        pz[k] = bp[gi + 2];
        md[k] = 1e10f;
        lx[j] = px[k]; ly[j] = py[k]; lz[j] = pz[k];
    }
    const u32 relt = (u32)(NPTS - 1) - (u32)(gbase + tid);

    float c1x = bp[0], c1y = bp[1], c1z = bp[2];
    float c2x = c1x, c2y = c1y, c2z = c1z;
    bool have2 = false;
    if (blk == 0 && tid == 0) {
        out[b * MSEL] = 0.0f;
        float* oxyz = out + BATCHES * MSEL;
        oxyz[(size_t)(b * MSEL) * 3 + 0] = c1x;
        oxyz[(size_t)(b * MSEL) * 3 + 1] = c1y;
        oxyz[(size_t)(b * MSEL) * 3 + 2] = c1z;
    }
    __syncthreads();

    const int wv = tid >> 6;
    const int ln = tid & 63;
    bool useAgent = false;
    int s = 1;

    for (int rc = 1; s < MSEL; ++rc) {
        // ---- md update (1 or 2 centers, exact ref order) + top-2 track ----
        u64 a1 = 0ull, a2 = 0ull;
        if (have2) {
            #pragma unroll
            for (int k = 0; k < PPT; ++k) {
                float dx = __fsub_rn(px[k], c1x);
                float dy = __fsub_rn(py[k], c1y);
                float dz = __fsub_rn(pz[k], c1z);
                float d1 = __fadd_rn(__fadd_rn(__fmul_rn(dx, dx),
                                               __fmul_rn(dy, dy)),
                                     __fmul_rn(dz, dz));
                float ex = __fsub_rn(px[k], c2x);
                float ey = __fsub_rn(py[k], c2y);
                float ez = __fsub_rn(pz[k], c2z);
                float d2 = __fadd_rn(__fadd_rn(__fmul_rn(ex, ex),
                                               __fmul_rn(ey, ey)),
                                     __fmul_rn(ez, ez));
                float nm = fminf(fminf(md[k], d1), d2);   // == ref sequential
                md[k] = nm;
                u64 key = ((u64)__float_as_uint(nm) << 17)
                        | (u64)(relt - (u32)(k * NTH));
                const bool gt = key > a1;
                const u64 mx2 = (key > a2) ? key : a2;
                a2 = gt ? a1 : mx2;
                a1 = gt ? key : a1;
            }
        } else {
            #pragma unroll
            for (int k = 0; k < PPT; ++k) {
                float dx = __fsub_rn(px[k], c1x);
                float dy = __fsub_rn(py[k], c1y);
                float dz = __fsub_rn(pz[k], c1z);
                float d1 = __fadd_rn(__fadd_rn(__fmul_rn(dx, dx),
                                               __fmul_rn(dy, dy)),
                                     __fmul_rn(dz, dz));
                float nm = fminf(md[k], d1);
                md[k] = nm;
                u64 key = ((u64)__float_as_uint(nm) << 17)
                        | (u64)(relt - (u32)(k * NTH));
                const bool gt = key > a1;
                const u64 mx2 = (key > a2) ? key : a2;
                a2 = gt ? a1 : mx2;
                a1 = gt ? key : a1;
            }
        }
        #pragma unroll
        for (int o = 32; o > 0; o >>= 1) {
            u64 t1 = __shfl_xor(a1, o, 64);
            u64 t2 = __shfl_xor(a2, o, 64);
            pmerge(a1, a2, t1, t2);
        }
        if (ln == 0) { wkey[wv][0] = a1; wkey[wv][1] = a2; }
        __syncthreads();

        const u32 tag = (u32)rc;            // 1..1023
        const int par = rc & 1;
        char* plbase = plb0 + ((size_t)(par * BATCHES + b) * NBLK) * pad;
        const size_t icb = (size_t)(par * BATCHES + b) * 64;

        // ---- wave1 lane0: agent-scope ic backups (fallback path) ----
        if (wv == 1 && ln == 0) {
            u64 k1 = wkey[0][0], k2 = wkey[0][1];
            #pragma unroll
            for (int w = 1; w < NWAVE; ++w)
                pmerge(k1, k2, wkey[w][0], wkey[w][1]);
            const u32 rel1 = (u32)(k1 & 0x1FFFFull);
            const u32 rel2 = (u32)(k2 & 0x1FFFFull);
            __hip_atomic_store(&ic[icb + 2 * blk],
                               ((k1 >> 17) << 27) | ((u64)rel1 << 10) | tag,
                               __ATOMIC_RELAXED, __HIP_MEMORY_SCOPE_AGENT);
            __hip_atomic_store(&ic[icb + 2 * blk + 1],
                               ((k2 >> 17) << 27) | ((u64)rel2 << 10) | tag,
                               __ATOMIC_RELAXED, __HIP_MEMORY_SCOPE_AGENT);
        }

        // ---- wave0: publish FIRST (lane0, EXEC-serialized), then poll ----
        if (wv == 0) {
            if (ln == 0) {
                u64 k1 = wkey[0][0], k2 = wkey[0][1];
                #pragma unroll
                for (int w = 1; w < NWAVE; ++w)
                    pmerge(k1, k2, wkey[w][0], wkey[w][1]);
                const u32 rel1 = (u32)(k1 & 0x1FFFFull);
                const u32 rel2 = (u32)(k2 & 0x1FFFFull);
                const int j1 = (int)((u32)(NPTS - 1) - rel1) - gbase;
                const int j2 = (int)((u32)(NPTS - 1) - rel2) - gbase;
                u32x4 G0, G1, G2;
                G0.x = (u32)(k1 >> 17);         G0.y = (rel1 << 10) | tag;
                G0.z = __float_as_uint(lx[j1]); G0.w = __float_as_uint(ly[j1]);
                G1.x = __float_as_uint(lz[j1]); G1.y = (u32)(k2 >> 17);
                G1.z = (rel2 << 10) | tag;      G1.w = __float_as_uint(lx[j2]);
                G2.x = __float_as_uint(ly[j2]); G2.y = __float_as_uint(lz[j2]);
                G2.z = tag;                     G2.w = 0u;
                u32* p = (u32*)(plbase + (size_t)blk * pad);
                asm volatile(
                    "global_store_dwordx4 %0, %1, off sc0\n\t"
                    "global_store_dwordx4 %2, %3, off sc0\n\t"
                    "global_store_dwordx4 %4, %5, off sc0"
                    :: "v"(p), "v"(G0), "v"(p + 4), "v"(G1), "v"(p + 8), "v"(G2)
                    : "memory");
            }
            // poll 32 slots, stop-on-fresh, sleep every miss (R4 protocol)
            u32x4 G0 = {0,0,0,0}, G1 = {0,0,0,0}, G2 = {0,0,0,0};
            bool done = (ln >= NBLK);
            if (!useAgent) {
                const u32* p = (const u32*)(plbase + (size_t)(ln & 31) * pad);
                int r = 0;
                for (;;) {
                    if (!done) {
                        u32x4 t0, t1, t2;
                        asm volatile(
                            "global_load_dwordx4 %0, %3, off sc0\n\t"
                            "global_load_dwordx4 %1, %4, off sc0\n\t"
                            "global_load_dwordx4 %2, %5, off sc0\n\t"
                            "s_waitcnt vmcnt(0)"
                            : "=&v"(t0), "=&v"(t1), "=&v"(t2)
                            : "v"(p), "v"(p + 4), "v"(p + 8)
                            : "memory");
                        if (((t0.y & 1023u) == tag) & ((t1.z & 1023u) == tag)
                            & (t2.z == tag)) {
                            G0 = t0; G1 = t1; G2 = t2; done = true;
                        }
                    }
                    if (__all(done)) break;
                    if (++r >= L2_TIMEOUT_ROUNDS) { useAgent = true; break; }
                    __builtin_amdgcn_s_sleep(1);
                }
            }
            if (!useAgent) {
                const u64 myk1 = ((u64)G0.x << 17) | (u64)(G0.y >> 10);
                u64 K1 = myk1;
                u64 K2 = ((u64)G1.y << 17) | (u64)(G1.z >> 10);
                #pragma unroll
                for (int o = 32; o > 0; o >>= 1) {
                    u64 t1 = __shfl_xor(K1, o, 64);
                    u64 t2 = __shfl_xor(K2, o, 64);
                    pmerge(K1, K2, t1, t2);
                }
                const u32 widx1 = (u32)(NPTS - 1) - (u32)(K1 & 0x1FFFFull);
                const u32 widx2 = (u32)(NPTS - 1) - (u32)(K2 & 0x1FFFFull);
                const int wb1 = (int)(widx1 >> 12);
                const int wbb = (int)(widx2 >> 12);
                const float x1 = __shfl(__uint_as_float(G0.z), wb1, 64);
                const float y1 = __shfl(__uint_as_float(G0.w), wb1, 64);
                const float z1 = __shfl(__uint_as_float(G1.x), wb1, 64);
                // runner-up: block wbb's primary (kb==K2) or secondary
                const u64  kb = __shfl(myk1, wbb, 64);
                const bool sp = (kb == K2);
                const float xp = __shfl(__uint_as_float(G0.z), wbb, 64);
                const float yp = __shfl(__uint_as_float(G0.w), wbb, 64);
                const float zp = __shfl(__uint_as_float(G1.x), wbb, 64);
                const float xs = __shfl(__uint_as_float(G1.w), wbb, 64);
                const float ys = __shfl(__uint_as_float(G2.x), wbb, 64);
                const float zs = __shfl(__uint_as_float(G2.y), wbb, 64);
                const float x2 = sp ? xp : xs;
                const float y2 = sp ? yp : ys;
                const float z2 = sp ? zp : zs;
                // exact speculation test: dist(c2,w1)^2 >= md[c2]
                const float ddx = __fsub_rn(x2, x1);
                const float ddy = __fsub_rn(y2, y1);
                const float ddz = __fsub_rn(z2, z1);
                const float dd  = __fadd_rn(__fadd_rn(__fmul_rn(ddx, ddx),
                                                      __fmul_rn(ddy, ddy)),
                                            __fmul_rn(ddz, ddz));
                const bool spec = (__float_as_uint(dd) >= (u32)(K2 >> 17))
                                  && (s + 1 < MSEL);
                if (ln == 0) {
                    curs[0] = x1; curs[1] = y1; curs[2] = z1;
                    curs[3] = x2; curs[4] = y2; curs[5] = z2;
                    curs[6] = spec ? 1.0f : 0.0f;
                    if (blk == 0) {
                        out[b * MSEL + s] = (float)widx1;
                        float* oxyz = out + BATCHES * MSEL;
                        oxyz[(size_t)(b * MSEL + s) * 3 + 0] = x1;
                        oxyz[(size_t)(b * MSEL + s) * 3 + 1] = y1;
                        oxyz[(size_t)(b * MSEL + s) * 3 + 2] = z1;
                        if (spec) {
                            out[b * MSEL + s + 1] = (float)widx2;
                            oxyz[(size_t)(b * MSEL + s + 1) * 3 + 0] = x2;
                            oxyz[(size_t)(b * MSEL + s + 1) * 3 + 1] = y2;
                            oxyz[(size_t)(b * MSEL + s + 1) * 3 + 2] = z2;
                        }
                    }
                }
            } else {
                // ---- sticky agent-scope fallback: keys from ic, xyz from pts
                const int ii = (ln < 32) ? (2 * ln) : (2 * (ln - 32) + 1);
                u64 sv = 0ull;
                for (;;) {
                    sv = __hip_atomic_load(&ic[icb + ii], __ATOMIC_RELAXED,
                                           __HIP_MEMORY_SCOPE_AGENT);
                    if (__all((u32)(sv & 1023ull) == (tag & 1023u))) break;
                    __builtin_amdgcn_s_sleep(1);
                }
                u64 K1 = ((sv >> 27) << 17) | ((sv >> 10) & 0x1FFFFull);
                u64 K2 = 0ull;
                #pragma unroll
                for (int o = 32; o > 0; o >>= 1) {
                    u64 t1 = __shfl_xor(K1, o, 64);
                    u64 t2 = __shfl_xor(K2, o, 64);
                    pmerge(K1, K2, t1, t2);
                }
                const u32 widx1 = (u32)(NPTS - 1) - (u32)(K1 & 0x1FFFFull);
                const u32 widx2 = (u32)(NPTS - 1) - (u32)(K2 & 0x1FFFFull);
                if (ln == 0) {
                    const float x1 = bp[(size_t)widx1 * 3 + 0];
                    const float y1 = bp[(size_t)widx1 * 3 + 1];
                    const float z1 = bp[(size_t)widx1 * 3 + 2];
                    const float x2 = bp[(size_t)widx2 * 3 + 0];
                    const float y2 = bp[(size_t)widx2 * 3 + 1];
                    const float z2 = bp[(size_t)widx2 * 3 + 2];
                    const float ddx = __fsub_rn(x2, x1);
                    const float ddy = __fsub_rn(y2, y1);
                    const float ddz = __fsub_rn(z2, z1);
                    const float dd  = __fadd_rn(__fadd_rn(__fmul_rn(ddx, ddx),
                                                          __fmul_rn(ddy, ddy)),
                                                __fmul_rn(ddz, ddz));
                    const bool spec = (__float_as_uint(dd) >= (u32)(K2 >> 17))
                                      && (s + 1 < MSEL);
                    curs[0] = x1; curs[1] = y1; curs[2] = z1;
                    curs[3] = x2; curs[4] = y2; curs[5] = z2;
                    curs[6] = spec ? 1.0f : 0.0f;
                    if (blk == 0) {
                        out[b * MSEL + s] = (float)widx1;
                        float* oxyz = out + BATCHES * MSEL;
                        oxyz[(size_t)(b * MSEL + s) * 3 + 0] = x1;
                        oxyz[(size_t)(b * MSEL + s) * 3 + 1] = y1;
                        oxyz[(size_t)(b * MSEL + s) * 3 + 2] = z1;
                        if (spec) {
                            out[b * MSEL + s + 1] = (float)widx2;
                            oxyz[(size_t)(b * MSEL + s + 1) * 3 + 0] = x2;
                            oxyz[(size_t)(b * MSEL + s + 1) * 3 + 1] = y2;
                            oxyz[(size_t)(b * MSEL + s + 1) * 3 + 2] = z2;
                        }
                    }
                }
            }
        }
        __syncthreads();
        c1x = curs[0]; c1y = curs[1]; c1z = curs[2];
        c2x = curs[3]; c2y = curs[4]; c2z = curs[5];
        have2 = (curs[6] != 0.0f);
        s += 1 + (have2 ? 1 : 0);
    }
}

extern "C" void kernel_launch(void* const* d_in, const int* in_sizes, int n_in,
                              void* d_out, int out_size, void* d_ws, size_t ws_size,
                              hipStream_t stream) {
    const float* pts = (const float*)d_in[0];
    float* out = (float*)d_out;

    // slots 2*8*32*pad + ic 8KB
    int pad = 64;
    if (ws_size >= (size_t)(2 * BATCHES * NBLK * 128 + 8192 + 1024)) pad = 128;

    fps_kernel<<<dim3(BATCHES * NBLK), dim3(NTH), 0, stream>>>(
        pts, out, (char*)d_ws, pad);
}